// Round 1
// baseline (1043.896 us; speedup 1.0000x reference)
//
#include <hip/hip_runtime.h>
#include <hip/hip_bf16.h>

#define MIDF 256
#define OUTF 64
#define CF 64
#define TWO_C 128
#define BN_EPS 1e-5f

// ---------------- zero S and cnt ----------------
__global__ void k_zero(float4* __restrict__ p, int n4) {
  int i = blockIdx.x * blockDim.x + threadIdx.x;
  int st = gridDim.x * blockDim.x;
  float4 z = make_float4(0.f, 0.f, 0.f, 0.f);
  for (; i < n4; i += st) p[i] = z;
}

// ---------------- edge scatter: one wave per edge ----------------
// lane f handles feature f: S[row][f] += x[col][f]; S[row][64+f] += x[col][f]*ea
__global__ void k_scatter(const float* __restrict__ x, const int* __restrict__ ei,
                          const float* __restrict__ ea, float* __restrict__ S,
                          float* __restrict__ cnt, int E) {
  int lane = threadIdx.x & 63;
  int wave = (blockIdx.x * blockDim.x + threadIdx.x) >> 6;
  int nw = (gridDim.x * blockDim.x) >> 6;
  for (int e = wave; e < E; e += nw) {
    int row = ei[e];        // edge_index[0][e] : destination
    int col = ei[E + e];    // edge_index[1][e] : source
    float w = ea[e];
    float xv = x[col * CF + lane];           // coalesced 256B
    float* dst = S + (size_t)row * TWO_C + lane;
    atomicAdd(dst, xv);
    atomicAdd(dst + CF, xv * w);
    if (lane == 0) atomicAdd(cnt + row, 1.0f);
  }
}

// ---------------- GEMM1: agg[N,128] @ W1[128,256] + b1, ReLU -> h ----------------
// block = 256 threads, tile = 16 rows x 256 cols, thread = 4x4 register tile.
// W1 fully resident in LDS (128KB); A-tile transposed [k][r] (8KB).
__global__ __launch_bounds__(256) void k_gemm1(const float* __restrict__ S,
    const float* __restrict__ cnt, const float* __restrict__ W1,
    const float* __restrict__ b1, float* __restrict__ h, int n, int ntiles) {
  __shared__ float Wl[TWO_C * MIDF];   // [k][c] 128x256
  __shared__ float Al[TWO_C * 16];     // [k][r] 128x16
  int tid = threadIdx.x;
  for (int i = tid; i < TWO_C * MIDF / 4; i += 256)
    ((float4*)Wl)[i] = ((const float4*)W1)[i];
  int cg = tid & 63;   // 64 col-groups x 4 cols = 256 cols
  int rg = tid >> 6;   // 4 row-groups x 4 rows  = 16 rows
  float4 b1v = ((const float4*)b1)[cg];
  for (int t = blockIdx.x; t < ntiles; t += gridDim.x) {
    int r0 = t * 16;
    __syncthreads();
    // stage A-tile: 16 rows x 128 k, scaled by 1/max(cnt,1), transposed store
#pragma unroll
    for (int s = 0; s < 2; ++s) {
      int rr = (tid & 7) + 8 * s;   // 0..15
      int c4 = tid >> 3;            // 0..31 float4 chunks per row
      int r = r0 + rr;
      float4 v = make_float4(0.f, 0.f, 0.f, 0.f);
      float inv = 0.f;
      if (r < n) {
        float c = cnt[r];
        inv = 1.0f / fmaxf(c, 1.0f);
        v = ((const float4*)(S + (size_t)r * TWO_C))[c4];
      }
      int k = c4 * 4;
      Al[(k + 0) * 16 + rr] = v.x * inv;
      Al[(k + 1) * 16 + rr] = v.y * inv;
      Al[(k + 2) * 16 + rr] = v.z * inv;
      Al[(k + 3) * 16 + rr] = v.w * inv;
    }
    __syncthreads();
    float acc[4][4];
#pragma unroll
    for (int i = 0; i < 4; ++i)
#pragma unroll
      for (int j = 0; j < 4; ++j) acc[i][j] = 0.f;
#pragma unroll 8
    for (int k = 0; k < TWO_C; ++k) {
      float4 a = *(const float4*)(Al + k * 16 + 4 * rg);      // broadcast b128
      float4 w = *(const float4*)(Wl + k * MIDF + 4 * cg);    // conflict-free b128
      float av[4] = {a.x, a.y, a.z, a.w};
      float wv[4] = {w.x, w.y, w.z, w.w};
#pragma unroll
      for (int i = 0; i < 4; ++i)
#pragma unroll
        for (int j = 0; j < 4; ++j) acc[i][j] = fmaf(av[i], wv[j], acc[i][j]);
    }
#pragma unroll
    for (int i = 0; i < 4; ++i) {
      int r = r0 + 4 * rg + i;
      if (r < n) {
        float4 o;
        o.x = fmaxf(acc[i][0] + b1v.x, 0.f);
        o.y = fmaxf(acc[i][1] + b1v.y, 0.f);
        o.z = fmaxf(acc[i][2] + b1v.z, 0.f);
        o.w = fmaxf(acc[i][3] + b1v.w, 0.f);
        ((float4*)(h + (size_t)r * MIDF))[cg] = o;
      }
    }
  }
}

// ---------------- BN stats: per-block column partials, then finalize ----------------
__global__ void k_part(const float* __restrict__ h, float* __restrict__ part, int n) {
  int c = threadIdx.x;   // 256 threads <-> 256 cols
  float s = 0.f, q = 0.f;
#pragma unroll 4
  for (int r = blockIdx.x; r < n; r += gridDim.x) {
    float v = h[(size_t)r * MIDF + c];
    s += v;
    q += v * v;
  }
  part[blockIdx.x * 512 + c] = s;
  part[blockIdx.x * 512 + 256 + c] = q;
}

__global__ void k_final(const float* __restrict__ part, const float* __restrict__ gamma,
                        const float* __restrict__ beta, float* __restrict__ stats,
                        int nb, float invN) {
  int c = threadIdx.x;
  float s = 0.f, q = 0.f;
#pragma unroll 8
  for (int b = 0; b < nb; ++b) {
    s += part[b * 512 + c];
    q += part[b * 512 + 256 + c];
  }
  float mu = s * invN;
  float var = q * invN - mu * mu;           // biased var, as torch BN
  float sc = gamma[c] * rsqrtf(var + BN_EPS);
  stats[c] = sc;                            // scale
  stats[MIDF + c] = beta[c] - mu * sc;      // shift
}

// ---------------- GEMM2: hn[N,256] @ W2[256,64] + b2 -> out ----------------
// block = 256 threads, tile = 64 rows x 64 cols, thread = 4x4 register tile.
// W2 in LDS (64KB); normalized A-tile transposed [k][r] stride 68 (69.6KB).
#define ASTR 68
__global__ __launch_bounds__(256) void k_gemm2(const float* __restrict__ h,
    const float* __restrict__ stats, const float* __restrict__ W2,
    const float* __restrict__ b2, float* __restrict__ out, int n, int ntiles) {
  __shared__ float Wl[MIDF * OUTF];    // [k][c] 256x64
  __shared__ float Al[MIDF * ASTR];    // [k][r] 256x(64+4 pad)
  int tid = threadIdx.x;
  for (int i = tid; i < MIDF * OUTF / 4; i += 256)
    ((float4*)Wl)[i] = ((const float4*)W2)[i];
  int cg = tid & 15;   // 16 col-groups x 4 cols = 64 cols
  int rg = tid >> 4;   // 16 row-groups x 4 rows = 64 rows
  float4 b2v = ((const float4*)b2)[cg];
  for (int t = blockIdx.x; t < ntiles; t += gridDim.x) {
    int r0 = t * 64;
    __syncthreads();
    // stage normalized A-tile: 64 rows x 256 k, transposed
#pragma unroll
    for (int s = 0; s < 16; ++s) {
      int rr = (tid & 7) + 8 * (s & 7);        // 0..63
      int c4 = (tid >> 3) + 32 * (s >> 3);     // 0..63 float4 chunks per row
      int r = r0 + rr;
      float4 v = make_float4(0.f, 0.f, 0.f, 0.f);
      if (r < n) v = ((const float4*)(h + (size_t)r * MIDF))[c4];
      float4 sc = ((const float4*)stats)[c4];
      float4 sh = ((const float4*)(stats + MIDF))[c4];
      int k = c4 * 4;
      Al[(k + 0) * ASTR + rr] = v.x * sc.x + sh.x;
      Al[(k + 1) * ASTR + rr] = v.y * sc.y + sh.y;
      Al[(k + 2) * ASTR + rr] = v.z * sc.z + sh.z;
      Al[(k + 3) * ASTR + rr] = v.w * sc.w + sh.w;
    }
    __syncthreads();
    float acc[4][4];
#pragma unroll
    for (int i = 0; i < 4; ++i)
#pragma unroll
      for (int j = 0; j < 4; ++j) acc[i][j] = 0.f;
#pragma unroll 8
    for (int k = 0; k < MIDF; ++k) {
      float4 a = *(const float4*)(Al + k * ASTR + 4 * rg);
      float4 w = *(const float4*)(Wl + k * OUTF + 4 * cg);
      float av[4] = {a.x, a.y, a.z, a.w};
      float wv[4] = {w.x, w.y, w.z, w.w};
#pragma unroll
      for (int i = 0; i < 4; ++i)
#pragma unroll
        for (int j = 0; j < 4; ++j) acc[i][j] = fmaf(av[i], wv[j], acc[i][j]);
    }
#pragma unroll
    for (int i = 0; i < 4; ++i) {
      int r = r0 + 4 * rg + i;
      if (r < n) {
        float4 o = make_float4(acc[i][0] + b2v.x, acc[i][1] + b2v.y,
                               acc[i][2] + b2v.z, acc[i][3] + b2v.w);
        ((float4*)(out + (size_t)r * OUTF))[cg] = o;
      }
    }
  }
}

extern "C" void kernel_launch(void* const* d_in, const int* in_sizes, int n_in,
                              void* d_out, int out_size, void* d_ws, size_t ws_size,
                              hipStream_t stream) {
  const float* x     = (const float*)d_in[0];
  const int*   ei    = (const int*)d_in[1];
  const float* ea    = (const float*)d_in[2];
  const float* W1    = (const float*)d_in[4];
  const float* b1    = (const float*)d_in[5];
  const float* gamma = (const float*)d_in[6];
  const float* beta  = (const float*)d_in[7];
  const float* W2    = (const float*)d_in[8];
  const float* b2    = (const float*)d_in[9];
  float* out = (float*)d_out;
  int E = in_sizes[2];   // edge_attr count = E
  int n = in_sizes[3];   // batch count = N

  // workspace layout (floats)
  float* ws    = (float*)d_ws;
  float* S     = ws;                           // n*128
  float* cnt   = S + (size_t)n * TWO_C;        // n
  float* h     = cnt + n;                      // n*256
  float* part  = h + (size_t)n * MIDF;         // 256*512
  float* stats = part + 256 * 512;             // 512

  int zero4 = (n * (TWO_C + 1) + 3) / 4;       // S + cnt contiguous
  hipLaunchKernelGGL(k_zero, dim3(1024), dim3(256), 0, stream, (float4*)S, zero4);
  hipLaunchKernelGGL(k_scatter, dim3(2048), dim3(256), 0, stream, x, ei, ea, S, cnt, E);
  int t1 = (n + 15) / 16;
  hipLaunchKernelGGL(k_gemm1, dim3(250), dim3(256), 0, stream, S, cnt, W1, b1, h, n, t1);
  hipLaunchKernelGGL(k_part, dim3(256), dim3(256), 0, stream, h, part, n);
  hipLaunchKernelGGL(k_final, dim3(1), dim3(256), 0, stream, part, gamma, beta, stats,
                     256, 1.0f / (float)n);
  int t2 = (n + 63) / 64;
  hipLaunchKernelGGL(k_gemm2, dim3(256), dim3(256), 0, stream, h, stats, W2, b2, out, n, t2);
}

// Round 2
// 785.363 us; speedup vs baseline: 1.3292x; 1.3292x over previous
//
#include <hip/hip_runtime.h>
#include <hip/hip_bf16.h>

#define MIDF 256
#define OUTF 64
#define CF 64
#define TWO_C 128
#define BN_EPS 1e-5f

// ---------------- generic zero ----------------
__global__ void k_zero(float4* __restrict__ p, int n4) {
  int i = blockIdx.x * blockDim.x + threadIdx.x;
  int st = gridDim.x * blockDim.x;
  float4 z = make_float4(0.f, 0.f, 0.f, 0.f);
  for (; i < n4; i += st) p[i] = z;
}

// ---------------- degree histogram (int atomics) ----------------
__global__ void k_hist(const int* __restrict__ ei, int* __restrict__ hist, int E) {
  int e = blockIdx.x * blockDim.x + threadIdx.x;
  if (e < E) atomicAdd(&hist[ei[e]], 1);
}

// ---------------- one-block exclusive scan (4 elems/thread, shfl) ----------------
__global__ __launch_bounds__(1024) void k_scan(const int* __restrict__ hist,
    int* __restrict__ starts, int* __restrict__ cursor, int n) {
  __shared__ int wsum[16];
  __shared__ int carry;
  int tid = threadIdx.x, lane = tid & 63, w = tid >> 6;
  if (tid == 0) carry = 0;
  __syncthreads();
  int nchunk = (n + 4095) >> 12;
  for (int c = 0; c < nchunk; ++c) {
    int i0 = (c << 12) + tid * 4;
    int4 v = make_int4(0, 0, 0, 0);
    if (i0 + 3 < n) v = *(const int4*)(hist + i0);
    else {
      if (i0 + 0 < n) v.x = hist[i0 + 0];
      if (i0 + 1 < n) v.y = hist[i0 + 1];
      if (i0 + 2 < n) v.z = hist[i0 + 2];
    }
    int ts = v.x + v.y + v.z + v.w;
    int sc = ts;
#pragma unroll
    for (int d = 1; d < 64; d <<= 1) {
      int t = __shfl_up(sc, d);
      if (lane >= d) sc += t;
    }
    if (lane == 63) wsum[w] = sc;
    __syncthreads();
    if (tid == 0) {
      int acc = carry;
#pragma unroll
      for (int j = 0; j < 16; ++j) { int t = wsum[j]; wsum[j] = acc; acc += t; }
      carry = acc;
    }
    __syncthreads();
    int e0 = wsum[w] + sc - ts;
    int e1 = e0 + v.x, e2 = e1 + v.y, e3 = e2 + v.z;
    if (i0 + 0 < n) { starts[i0 + 0] = e0; cursor[i0 + 0] = e0; }
    if (i0 + 1 < n) { starts[i0 + 1] = e1; cursor[i0 + 1] = e1; }
    if (i0 + 2 < n) { starts[i0 + 2] = e2; cursor[i0 + 2] = e2; }
    if (i0 + 3 < n) { starts[i0 + 3] = e3; cursor[i0 + 3] = e3; }
    __syncthreads();
  }
  if (tid == 0) starts[n] = carry;
}

// ---------------- reorder edges into CSR buckets ----------------
__global__ void k_reorder(const int* __restrict__ ei, const float* __restrict__ ea,
                          int* __restrict__ cursor, uint2* __restrict__ eb, int E) {
  int e = blockIdx.x * blockDim.x + threadIdx.x;
  if (e < E) {
    int r = ei[e];
    int pos = atomicAdd(&cursor[r], 1);
    eb[pos] = make_uint2((unsigned)ei[E + e], __float_as_uint(ea[e]));
  }
}

// ---------------- segmented mean: one wave per node ----------------
__global__ void k_agg(const float* __restrict__ x, const uint2* __restrict__ eb,
                      const int* __restrict__ starts, float* __restrict__ agg, int n) {
  int lane = threadIdx.x & 63;
  int wave = (blockIdx.x * blockDim.x + threadIdx.x) >> 6;
  int nw = (gridDim.x * blockDim.x) >> 6;
  for (int v = wave; v < n; v += nw) {
    int s = starts[v], e = starts[v + 1];
    float a0 = 0.f, a1 = 0.f;
    for (int i = s; i < e; ++i) {
      uint2 p = eb[i];                       // broadcast (same addr all lanes)
      float xv = x[(size_t)p.x * CF + lane]; // coalesced 256B gather
      a0 += xv;
      a1 += xv * __uint_as_float(p.y);
    }
    float inv = 1.0f / fmaxf((float)(e - s), 1.0f);
    float* dst = agg + (size_t)v * TWO_C;
    dst[lane] = a0 * inv;
    dst[CF + lane] = a1 * inv;
  }
}

// ---------------- GEMM1: agg[N,128] @ W1[128,256] + b1, ReLU -> h ----------------
__global__ __launch_bounds__(256) void k_gemm1(const float* __restrict__ agg,
    const float* __restrict__ W1, const float* __restrict__ b1,
    float* __restrict__ h, int n, int ntiles) {
  __shared__ float Wl[TWO_C * MIDF];   // [k][c] 128x256
  __shared__ float Al[TWO_C * 16];     // [k][r] 128x16
  int tid = threadIdx.x;
  for (int i = tid; i < TWO_C * MIDF / 4; i += 256)
    ((float4*)Wl)[i] = ((const float4*)W1)[i];
  int cg = tid & 63;   // 64 col-groups x 4 cols = 256 cols
  int rg = tid >> 6;   // 4 row-groups x 4 rows  = 16 rows
  float4 b1v = ((const float4*)b1)[cg];
  for (int t = blockIdx.x; t < ntiles; t += gridDim.x) {
    int r0 = t * 16;
    __syncthreads();
#pragma unroll
    for (int s = 0; s < 2; ++s) {
      int rr = (tid & 7) + 8 * s;
      int c4 = tid >> 3;
      int r = r0 + rr;
      float4 v = make_float4(0.f, 0.f, 0.f, 0.f);
      if (r < n) v = ((const float4*)(agg + (size_t)r * TWO_C))[c4];
      int k = c4 * 4;
      Al[(k + 0) * 16 + rr] = v.x;
      Al[(k + 1) * 16 + rr] = v.y;
      Al[(k + 2) * 16 + rr] = v.z;
      Al[(k + 3) * 16 + rr] = v.w;
    }
    __syncthreads();
    float acc[4][4];
#pragma unroll
    for (int i = 0; i < 4; ++i)
#pragma unroll
      for (int j = 0; j < 4; ++j) acc[i][j] = 0.f;
#pragma unroll 8
    for (int k = 0; k < TWO_C; ++k) {
      float4 a = *(const float4*)(Al + k * 16 + 4 * rg);
      float4 w = *(const float4*)(Wl + k * MIDF + 4 * cg);
      float av[4] = {a.x, a.y, a.z, a.w};
      float wv[4] = {w.x, w.y, w.z, w.w};
#pragma unroll
      for (int i = 0; i < 4; ++i)
#pragma unroll
        for (int j = 0; j < 4; ++j) acc[i][j] = fmaf(av[i], wv[j], acc[i][j]);
    }
#pragma unroll
    for (int i = 0; i < 4; ++i) {
      int r = r0 + 4 * rg + i;
      if (r < n) {
        float4 o;
        o.x = fmaxf(acc[i][0] + b1v.x, 0.f);
        o.y = fmaxf(acc[i][1] + b1v.y, 0.f);
        o.z = fmaxf(acc[i][2] + b1v.z, 0.f);
        o.w = fmaxf(acc[i][3] + b1v.w, 0.f);
        ((float4*)(h + (size_t)r * MIDF))[cg] = o;
      }
    }
  }
}

// ---------------- BN stats ----------------
__global__ void k_part(const float* __restrict__ h, float* __restrict__ part, int n) {
  int c = threadIdx.x;
  float s = 0.f, q = 0.f;
#pragma unroll 4
  for (int r = blockIdx.x; r < n; r += gridDim.x) {
    float v = h[(size_t)r * MIDF + c];
    s += v;
    q += v * v;
  }
  part[blockIdx.x * 512 + c] = s;
  part[blockIdx.x * 512 + 256 + c] = q;
}

__global__ void k_final(const float* __restrict__ part, const float* __restrict__ gamma,
                        const float* __restrict__ beta, float* __restrict__ stats,
                        int nb, float invN) {
  int c = threadIdx.x;
  float s = 0.f, q = 0.f;
#pragma unroll 8
  for (int b = 0; b < nb; ++b) {
    s += part[b * 512 + c];
    q += part[b * 512 + 256 + c];
  }
  float mu = s * invN;
  float var = q * invN - mu * mu;
  float sc = gamma[c] * rsqrtf(var + BN_EPS);
  stats[c] = sc;
  stats[MIDF + c] = beta[c] - mu * sc;
}

// ---------------- GEMM2: hn[N,256] @ W2[256,64] + b2 -> out ----------------
#define ASTR 68
__global__ __launch_bounds__(256) void k_gemm2(const float* __restrict__ h,
    const float* __restrict__ stats, const float* __restrict__ W2,
    const float* __restrict__ b2, float* __restrict__ out, int n, int ntiles) {
  __shared__ float Wl[MIDF * OUTF];
  __shared__ float Al[MIDF * ASTR];
  int tid = threadIdx.x;
  for (int i = tid; i < MIDF * OUTF / 4; i += 256)
    ((float4*)Wl)[i] = ((const float4*)W2)[i];
  int cg = tid & 15;
  int rg = tid >> 4;
  float4 b2v = ((const float4*)b2)[cg];
  for (int t = blockIdx.x; t < ntiles; t += gridDim.x) {
    int r0 = t * 64;
    __syncthreads();
#pragma unroll
    for (int s = 0; s < 16; ++s) {
      int rr = (tid & 7) + 8 * (s & 7);
      int c4 = (tid >> 3) + 32 * (s >> 3);
      int r = r0 + rr;
      float4 v = make_float4(0.f, 0.f, 0.f, 0.f);
      if (r < n) v = ((const float4*)(h + (size_t)r * MIDF))[c4];
      float4 sc = ((const float4*)stats)[c4];
      float4 sh = ((const float4*)(stats + MIDF))[c4];
      int k = c4 * 4;
      Al[(k + 0) * ASTR + rr] = v.x * sc.x + sh.x;
      Al[(k + 1) * ASTR + rr] = v.y * sc.y + sh.y;
      Al[(k + 2) * ASTR + rr] = v.z * sc.z + sh.z;
      Al[(k + 3) * ASTR + rr] = v.w * sc.w + sh.w;
    }
    __syncthreads();
    float acc[4][4];
#pragma unroll
    for (int i = 0; i < 4; ++i)
#pragma unroll
      for (int j = 0; j < 4; ++j) acc[i][j] = 0.f;
#pragma unroll 8
    for (int k = 0; k < MIDF; ++k) {
      float4 a = *(const float4*)(Al + k * ASTR + 4 * rg);
      float4 w = *(const float4*)(Wl + k * OUTF + 4 * cg);
      float av[4] = {a.x, a.y, a.z, a.w};
      float wv[4] = {w.x, w.y, w.z, w.w};
#pragma unroll
      for (int i = 0; i < 4; ++i)
#pragma unroll
        for (int j = 0; j < 4; ++j) acc[i][j] = fmaf(av[i], wv[j], acc[i][j]);
    }
#pragma unroll
    for (int i = 0; i < 4; ++i) {
      int r = r0 + 4 * rg + i;
      if (r < n) {
        float4 o = make_float4(acc[i][0] + b2v.x, acc[i][1] + b2v.y,
                               acc[i][2] + b2v.z, acc[i][3] + b2v.w);
        ((float4*)(out + (size_t)r * OUTF))[cg] = o;
      }
    }
  }
}

extern "C" void kernel_launch(void* const* d_in, const int* in_sizes, int n_in,
                              void* d_out, int out_size, void* d_ws, size_t ws_size,
                              hipStream_t stream) {
  const float* x     = (const float*)d_in[0];
  const int*   ei    = (const int*)d_in[1];
  const float* ea    = (const float*)d_in[2];
  const float* W1    = (const float*)d_in[4];
  const float* b1    = (const float*)d_in[5];
  const float* gamma = (const float*)d_in[6];
  const float* beta  = (const float*)d_in[7];
  const float* W2    = (const float*)d_in[8];
  const float* b2    = (const float*)d_in[9];
  float* out = (float*)d_out;
  int E = in_sizes[2];
  int n = in_sizes[3];

  // workspace layout
  float* ws    = (float*)d_ws;
  float* agg   = ws;                             // n*128 f32
  float* h     = agg + (size_t)n * TWO_C;        // n*256 f32
  float* part  = h + (size_t)n * MIDF;           // 256*512 f32
  float* stats = part + 256 * 512;               // 512 f32
  int*   hist  = (int*)(stats + 512);            // n
  int*   starts= hist + n;                       // n+1
  int*   cursor= starts + n + 1;                 // n
  uint2* eb    = (uint2*)h;                      // alias: used before h is written

  int eblk = (E + 255) / 256;
  hipLaunchKernelGGL(k_zero, dim3(64), dim3(256), 0, stream,
                     (float4*)hist, (n + 3) / 4);
  hipLaunchKernelGGL(k_hist, dim3(eblk), dim3(256), 0, stream, ei, hist, E);
  hipLaunchKernelGGL(k_scan, dim3(1), dim3(1024), 0, stream, hist, starts, cursor, n);
  hipLaunchKernelGGL(k_reorder, dim3(eblk), dim3(256), 0, stream, ei, ea, cursor, eb, E);
  hipLaunchKernelGGL(k_agg, dim3(4096), dim3(256), 0, stream, x, eb, starts, agg, n);
  int t1 = (n + 15) / 16;
  hipLaunchKernelGGL(k_gemm1, dim3(250), dim3(256), 0, stream, agg, W1, b1, h, n, t1);
  hipLaunchKernelGGL(k_part, dim3(256), dim3(256), 0, stream, h, part, n);
  hipLaunchKernelGGL(k_final, dim3(1), dim3(256), 0, stream, part, gamma, beta, stats,
                     256, 1.0f / (float)n);
  int t2 = (n + 63) / 64;
  hipLaunchKernelGGL(k_gemm2, dim3(256), dim3(256), 0, stream, h, stats, W2, b2, out, n, t2);
}

// Round 3
// 482.971 us; speedup vs baseline: 2.1614x; 1.6261x over previous
//
#include <hip/hip_runtime.h>
#include <hip/hip_bf16.h>

#define MIDF 256
#define OUTF 64
#define CF 64
#define TWO_C 128
#define BN_EPS 1e-5f

typedef __attribute__((ext_vector_type(8))) short bf16x8;
typedef __attribute__((ext_vector_type(4))) float f32x4;

__device__ __forceinline__ ushort f2bf(float f) {
  union { float f; unsigned u; } v; v.f = f;
  return (ushort)((v.u + 0x7fffu + ((v.u >> 16) & 1u)) >> 16);
}
__device__ __forceinline__ float bf2f(unsigned u16) {
  union { unsigned u; float f; } v; v.u = u16 << 16;
  return v.f;
}

// ---------------- generic zero ----------------
__global__ void k_zero(float4* __restrict__ p, int n4) {
  int i = blockIdx.x * blockDim.x + threadIdx.x;
  int st = gridDim.x * blockDim.x;
  float4 z = make_float4(0.f, 0.f, 0.f, 0.f);
  for (; i < n4; i += st) p[i] = z;
}

// ---------------- degree histogram ----------------
__global__ void k_hist(const int* __restrict__ ei, int* __restrict__ hist, int E) {
  int e = blockIdx.x * blockDim.x + threadIdx.x;
  if (e < E) atomicAdd(&hist[ei[e]], 1);
}

// ---------------- one-block exclusive scan ----------------
__global__ __launch_bounds__(1024) void k_scan(const int* __restrict__ hist,
    int* __restrict__ starts, int* __restrict__ cursor, int n) {
  __shared__ int wsum[16];
  __shared__ int carry;
  int tid = threadIdx.x, lane = tid & 63, w = tid >> 6;
  if (tid == 0) carry = 0;
  __syncthreads();
  int nchunk = (n + 4095) >> 12;
  for (int c = 0; c < nchunk; ++c) {
    int i0 = (c << 12) + tid * 4;
    int4 v = make_int4(0, 0, 0, 0);
    if (i0 + 3 < n) v = *(const int4*)(hist + i0);
    else {
      if (i0 + 0 < n) v.x = hist[i0 + 0];
      if (i0 + 1 < n) v.y = hist[i0 + 1];
      if (i0 + 2 < n) v.z = hist[i0 + 2];
    }
    int ts = v.x + v.y + v.z + v.w;
    int sc = ts;
#pragma unroll
    for (int d = 1; d < 64; d <<= 1) {
      int t = __shfl_up(sc, d);
      if (lane >= d) sc += t;
    }
    if (lane == 63) wsum[w] = sc;
    __syncthreads();
    if (tid == 0) {
      int acc = carry;
#pragma unroll
      for (int j = 0; j < 16; ++j) { int t = wsum[j]; wsum[j] = acc; acc += t; }
      carry = acc;
    }
    __syncthreads();
    int e0 = wsum[w] + sc - ts;
    int e1 = e0 + v.x, e2 = e1 + v.y, e3 = e2 + v.z;
    if (i0 + 0 < n) { starts[i0 + 0] = e0; cursor[i0 + 0] = e0; }
    if (i0 + 1 < n) { starts[i0 + 1] = e1; cursor[i0 + 1] = e1; }
    if (i0 + 2 < n) { starts[i0 + 2] = e2; cursor[i0 + 2] = e2; }
    if (i0 + 3 < n) { starts[i0 + 3] = e3; cursor[i0 + 3] = e3; }
    __syncthreads();
  }
  if (tid == 0) starts[n] = carry;
}

// ---------------- reorder edges into CSR buckets ----------------
__global__ void k_reorder(const int* __restrict__ ei, const float* __restrict__ ea,
                          int* __restrict__ cursor, uint2* __restrict__ eb, int E) {
  int e = blockIdx.x * blockDim.x + threadIdx.x;
  if (e < E) {
    int r = ei[e];
    int pos = atomicAdd(&cursor[r], 1);
    eb[pos] = make_uint2((unsigned)ei[E + e], __float_as_uint(ea[e]));
  }
}

// ---------------- segmented mean: one wave per node, bf16 out ----------------
__global__ void k_agg(const float* __restrict__ x, const uint2* __restrict__ eb,
                      const int* __restrict__ starts, ushort* __restrict__ agg, int n) {
  int lane = threadIdx.x & 63;
  int wave = (blockIdx.x * blockDim.x + threadIdx.x) >> 6;
  int nw = (gridDim.x * blockDim.x) >> 6;
  for (int v = wave; v < n; v += nw) {
    int s = starts[v], e = starts[v + 1];
    float a0 = 0.f, a1 = 0.f;
    int i = s;
    for (; i + 4 <= e; i += 4) {
      uint2 p0 = eb[i], p1 = eb[i + 1], p2 = eb[i + 2], p3 = eb[i + 3];
      float x0 = x[(size_t)p0.x * CF + lane];
      float x1 = x[(size_t)p1.x * CF + lane];
      float x2 = x[(size_t)p2.x * CF + lane];
      float x3 = x[(size_t)p3.x * CF + lane];
      a0 += (x0 + x1) + (x2 + x3);
      a1 += (x0 * __uint_as_float(p0.y) + x1 * __uint_as_float(p1.y)) +
            (x2 * __uint_as_float(p2.y) + x3 * __uint_as_float(p3.y));
    }
    for (; i < e; ++i) {
      uint2 p = eb[i];
      float xv = x[(size_t)p.x * CF + lane];
      a0 += xv;
      a1 += xv * __uint_as_float(p.y);
    }
    float inv = 1.0f / fmaxf((float)(e - s), 1.0f);
    ushort* dst = agg + (size_t)v * TWO_C;
    dst[lane] = f2bf(a0 * inv);
    dst[CF + lane] = f2bf(a1 * inv);
  }
}

// ---------------- GEMM1 (MFMA): agg[N,128]bf16 @ W1[128,256] + b1, ReLU -> h bf16 ----------------
// grid = 4 colgroups x 256 blocks; block = 4 waves; wave = 16 rows x 64 cols.
// B-fragments preloaded to registers once per block. Epilogue via LDS transpose.
__global__ __launch_bounds__(256, 3) void k_gemm1(const ushort* __restrict__ agg,
    const float* __restrict__ W1, const float* __restrict__ b1,
    ushort* __restrict__ h, int n, int ntiles) {
  int tid = threadIdx.x, w = tid >> 6, lane = tid & 63;
  int q = lane >> 4, l16 = lane & 15;
  int cg = blockIdx.x & 3;
  int colbase = cg * 64;
  bf16x8 Bf[4][4];
#pragma unroll
  for (int ct = 0; ct < 4; ++ct)
#pragma unroll
    for (int ks = 0; ks < 4; ++ks) {
      int c = colbase + ct * 16 + l16;
      int k0 = ks * 32 + q * 8;
#pragma unroll
      for (int j = 0; j < 8; ++j)
        Bf[ct][ks][j] = (short)f2bf(W1[(size_t)(k0 + j) * MIDF + c]);
    }
  float bias[4];
#pragma unroll
  for (int ct = 0; ct < 4; ++ct) bias[ct] = b1[colbase + ct * 16 + l16];
  __shared__ ushort tile[64 * 72];
  int nb = gridDim.x >> 2;
  for (int t = blockIdx.x >> 2; t < ntiles; t += nb) {
    int r0 = t * 64;
    int myrow = r0 + w * 16 + l16;
    bf16x8 Af[4];
#pragma unroll
    for (int ks = 0; ks < 4; ++ks) {
      bf16x8 av;
#pragma unroll
      for (int j = 0; j < 8; ++j) av[j] = 0;
      if (myrow < n) av = *(const bf16x8*)(agg + (size_t)myrow * TWO_C + ks * 32 + q * 8);
      Af[ks] = av;
    }
    f32x4 acc[4];
#pragma unroll
    for (int ct = 0; ct < 4; ++ct) acc[ct] = (f32x4){0.f, 0.f, 0.f, 0.f};
#pragma unroll
    for (int ks = 0; ks < 4; ++ks)
#pragma unroll
      for (int ct = 0; ct < 4; ++ct)
        acc[ct] = __builtin_amdgcn_mfma_f32_16x16x32_bf16(Af[ks], Bf[ct][ks], acc[ct], 0, 0, 0);
    __syncthreads();
#pragma unroll
    for (int ct = 0; ct < 4; ++ct)
#pragma unroll
      for (int r = 0; r < 4; ++r) {
        float vv = fmaxf(acc[ct][r] + bias[ct], 0.f);
        tile[(w * 16 + q * 4 + r) * 72 + ct * 16 + l16] = f2bf(vv);
      }
    __syncthreads();
    int row = tid >> 2, co = (tid & 3) * 16;
    int gr = r0 + row;
    if (gr < n) {
      const uint4* src = (const uint4*)(tile + row * 72 + co);
      uint4* dst = (uint4*)(h + (size_t)gr * MIDF + colbase + co);
      dst[0] = src[0];
      dst[1] = src[1];
    }
  }
}

// ---------------- BN stats partials (bf16 h) ----------------
__global__ __launch_bounds__(256) void k_part(const ushort* __restrict__ h,
                                              float* __restrict__ part, int n) {
  int tid = threadIdx.x;
  int rb = tid >> 6, cq = tid & 63;   // 4 cols per thread
  float s[4] = {0.f, 0.f, 0.f, 0.f}, qq[4] = {0.f, 0.f, 0.f, 0.f};
  for (int r = blockIdx.x * 4 + rb; r < n; r += gridDim.x * 4) {
    uint2 v = *(const uint2*)(h + (size_t)r * MIDF + cq * 4);
    float f0 = bf2f(v.x & 0xffff), f1 = bf2f(v.x >> 16);
    float f2 = bf2f(v.y & 0xffff), f3 = bf2f(v.y >> 16);
    s[0] += f0; qq[0] += f0 * f0;
    s[1] += f1; qq[1] += f1 * f1;
    s[2] += f2; qq[2] += f2 * f2;
    s[3] += f3; qq[3] += f3 * f3;
  }
  __shared__ float red[2048];
#pragma unroll
  for (int i = 0; i < 4; ++i) {
    red[rb * 512 + cq * 4 + i] = s[i];
    red[rb * 512 + 256 + cq * 4 + i] = qq[i];
  }
  __syncthreads();
  float ss = red[tid] + red[512 + tid] + red[1024 + tid] + red[1536 + tid];
  float sq = red[256 + tid] + red[768 + tid] + red[1280 + tid] + red[1792 + tid];
  part[blockIdx.x * 512 + tid] = ss;
  part[blockIdx.x * 512 + 256 + tid] = sq;
}

// ---------------- finalize BN + fold into W2/b2 ----------------
__global__ __launch_bounds__(256) void k_final(const float* __restrict__ part,
    const float* __restrict__ gamma, const float* __restrict__ beta,
    const float* __restrict__ W2, const float* __restrict__ b2,
    float* __restrict__ W2p, float* __restrict__ b2p, int nb, float invN) {
  __shared__ float scb[MIDF], shb[MIDF], red[256];
  int tid = threadIdx.x;
  float s = 0.f, q = 0.f;
#pragma unroll 8
  for (int b = 0; b < nb; ++b) {
    s += part[b * 512 + tid];
    q += part[b * 512 + 256 + tid];
  }
  float mu = s * invN;
  float var = q * invN - mu * mu;
  float sc = gamma[tid] * rsqrtf(var + BN_EPS);
  scb[tid] = sc;
  shb[tid] = beta[tid] - mu * sc;
  __syncthreads();
  // W2p[k][c] = sc[k]*W2[k][c];  b2p[c] = b2[c] + sum_k sh[k]*W2[k][c]
  float sp = 0.f;
  for (int i = tid; i < MIDF * OUTF; i += 256) {
    int k = i >> 6;
    float wv = W2[i];
    W2p[i] = scb[k] * wv;
    sp += shb[k] * wv;
  }
  red[tid] = sp;
  __syncthreads();
  if (tid < 64)
    b2p[tid] = b2[tid] + red[tid] + red[64 + tid] + red[128 + tid] + red[192 + tid];
}

// ---------------- GEMM2 (MFMA): h[N,256]bf16 @ W2p[256,64] + b2p -> out fp32 ----------------
__global__ __launch_bounds__(256, 2) void k_gemm2(const ushort* __restrict__ h,
    const float* __restrict__ W2p, const float* __restrict__ b2p,
    float* __restrict__ out, int n, int ntiles) {
  int tid = threadIdx.x, w = tid >> 6, lane = tid & 63;
  int q = lane >> 4, l16 = lane & 15;
  bf16x8 Bf[4][8];
#pragma unroll
  for (int ct = 0; ct < 4; ++ct)
#pragma unroll
    for (int ks = 0; ks < 8; ++ks) {
      int c = ct * 16 + l16;
      int k0 = ks * 32 + q * 8;
#pragma unroll
      for (int j = 0; j < 8; ++j)
        Bf[ct][ks][j] = (short)f2bf(W2p[(size_t)(k0 + j) * OUTF + c]);
    }
  float bias[4];
#pragma unroll
  for (int ct = 0; ct < 4; ++ct) bias[ct] = b2p[ct * 16 + l16];
  __shared__ float tile[64 * 68];
  for (int t = blockIdx.x; t < ntiles; t += gridDim.x) {
    int r0 = t * 64;
    int myrow = r0 + w * 16 + l16;
    f32x4 acc[4];
#pragma unroll
    for (int ct = 0; ct < 4; ++ct) acc[ct] = (f32x4){0.f, 0.f, 0.f, 0.f};
#pragma unroll
    for (int ks = 0; ks < 8; ++ks) {
      bf16x8 av;
#pragma unroll
      for (int j = 0; j < 8; ++j) av[j] = 0;
      if (myrow < n) av = *(const bf16x8*)(h + (size_t)myrow * MIDF + ks * 32 + q * 8);
#pragma unroll
      for (int ct = 0; ct < 4; ++ct)
        acc[ct] = __builtin_amdgcn_mfma_f32_16x16x32_bf16(av, Bf[ct][ks], acc[ct], 0, 0, 0);
    }
    __syncthreads();
#pragma unroll
    for (int ct = 0; ct < 4; ++ct)
#pragma unroll
      for (int r = 0; r < 4; ++r)
        tile[(w * 16 + q * 4 + r) * 68 + ct * 16 + l16] = acc[ct][r] + bias[ct];
    __syncthreads();
    int row = tid >> 2, co = (tid & 3) * 16;
    int gr = r0 + row;
    if (gr < n) {
      const float4* src = (const float4*)(tile + row * 68 + co);
      float4* dst = (float4*)(out + (size_t)gr * OUTF + co);
      dst[0] = src[0];
      dst[1] = src[1];
      dst[2] = src[2];
      dst[3] = src[3];
    }
  }
}

extern "C" void kernel_launch(void* const* d_in, const int* in_sizes, int n_in,
                              void* d_out, int out_size, void* d_ws, size_t ws_size,
                              hipStream_t stream) {
  const float* x     = (const float*)d_in[0];
  const int*   ei    = (const int*)d_in[1];
  const float* ea    = (const float*)d_in[2];
  const float* W1    = (const float*)d_in[4];
  const float* b1    = (const float*)d_in[5];
  const float* gamma = (const float*)d_in[6];
  const float* beta  = (const float*)d_in[7];
  const float* W2    = (const float*)d_in[8];
  const float* b2    = (const float*)d_in[9];
  float* out = (float*)d_out;
  int E = in_sizes[2];
  int n = in_sizes[3];

  // workspace layout
  char* ws = (char*)d_ws;
  ushort* agg = (ushort*)ws;                          // n*128 bf16
  ushort* h   = agg + (size_t)n * TWO_C;              // n*256 bf16
  float* part = (float*)(h + (size_t)n * MIDF);       // 256*512 f32
  float* W2p  = part + 256 * 512;                     // 16384 f32
  float* b2p  = W2p + MIDF * OUTF;                    // 64 f32
  int* hist   = (int*)(b2p + 64);                     // n
  int* starts = hist + n;                             // n+1
  int* cursor = starts + n + 1;                       // n
  uint2* eb   = (uint2*)h;                            // alias: dead before h written

  int eblk = (E + 255) / 256;
  hipLaunchKernelGGL(k_zero, dim3(64), dim3(256), 0, stream, (float4*)hist, (n + 3) / 4);
  hipLaunchKernelGGL(k_hist, dim3(eblk), dim3(256), 0, stream, ei, hist, E);
  hipLaunchKernelGGL(k_scan, dim3(1), dim3(1024), 0, stream, hist, starts, cursor, n);
  hipLaunchKernelGGL(k_reorder, dim3(eblk), dim3(256), 0, stream, ei, ea, cursor, eb, E);
  hipLaunchKernelGGL(k_agg, dim3(4096), dim3(256), 0, stream, x, eb, starts, agg, n);
  int nt = (n + 63) / 64;
  hipLaunchKernelGGL(k_gemm1, dim3(1024), dim3(256), 0, stream, agg, W1, b1, h, n, nt);
  hipLaunchKernelGGL(k_part, dim3(256), dim3(256), 0, stream, h, part, n);
  hipLaunchKernelGGL(k_final, dim3(1), dim3(256), 0, stream, part, gamma, beta,
                     W2, b2, W2p, b2p, 256, 1.0f / (float)n);
  hipLaunchKernelGGL(k_gemm2, dim3(512), dim3(256), 0, stream, h, W2p, b2p, out, n, nt);
}